// Round 5
// baseline (634.801 us; speedup 1.0000x reference)
//
#include <hip/hip_runtime.h>
#include <hip/hip_bf16.h>

#define B_    32
#define NBB_  16
#define C_    1024
#define NROI  512
#define KCONV 9216
#define SCALE_ (1.0f/16.0f)
#define EPS_  1e-5f

using f32x4  = __attribute__((ext_vector_type(4))) float;
using bf16x8 = __attribute__((ext_vector_type(8))) short;

__device__ __forceinline__ unsigned f2bf(float f) {
  union { float f; unsigned u; } x; x.f = f;
  unsigned r = x.u + 0x7fffu + ((x.u >> 16) & 1u);   // RNE
  return r >> 16;
}

__device__ __forceinline__ unsigned pk_bf16(float lo, float hi) {
  __hip_bfloat162 h = __float22bfloat162_rn(make_float2(lo, hi));
  return *reinterpret_cast<unsigned*>(&h);
}

__device__ __forceinline__ float hat_int(float t) {
  t = fminf(fmaxf(t, -1.f), 1.f);
  return t + 0.5f - 0.5f * t * fabsf(t);
}

__device__ __forceinline__ void glds16(const void* g, void* l) {
  __builtin_amdgcn_global_load_lds((const __attribute__((address_space(1))) void*)g,
                                   (__attribute__((address_space(3))) void*)l, 16, 0, 0);
}

// ---------------- K0: fused ROI weights + swizzled K-major W2d + counter zeroing.
// W2d layout: [b][s(0..7)][row(0..143)][slot^(row&7)][e]  (u16), k = s*64 + j*8 + e.
__global__ __launch_bounds__(192) void prep_w2d(const float* __restrict__ bbox,
                                                unsigned short* __restrict__ W2d,
                                                unsigned* __restrict__ ctr) {
  __shared__ float wyS[16*66], wxS[16*66];
  int b = blockIdx.x, tid = threadIdx.x;
  if (b == 0) { for (int i = tid; i < 256; i += 192) ctr[i] = 0; }
  for (int t = tid; t < 352; t += 192) {
    int n = t / 22, i = t - n * 22;
    float4 bb = ((const float4*)bbox)[b*16 + n];
    float x1 = bb.x * SCALE_, y1 = bb.y * SCALE_;
    float x2 = (bb.x + bb.z) * SCALE_, y2 = (bb.y + bb.w) * SCALE_;
    float bw = (x2 - x1) / 3.f, bh = (y2 - y1) / 3.f;
    float area = fmaxf(bw * bh, 0.f);
    float inv = area > 0.f ? 1.f / fmaxf(area, 1e-12f) : 0.f;
    float fi = (float)i;
#pragma unroll
    for (int q = 0; q < 3; ++q) {
      float sy = y1 + q * bh;
      wyS[n*66 + q*22 + i] = hat_int(sy + bh - fi) - hat_int(sy - fi);
      float sx = x1 + q * bw;
      wxS[n*66 + q*22 + i] = (hat_int(sx + bw - fi) - hat_int(sx - fi)) * inv;
    }
  }
  __syncthreads();
  if (tid < 144) {
    int r = tid;
    int n = r / 9, qp = r - n*9, q = qp / 3, p = qp - q*3;
    const float* wyp = wyS + n*66 + q*22;
    const float* wxp = wxS + n*66 + p*22;
    unsigned short* outB = W2d + (size_t)b * 8 * 9216;
    int rx = r & 7;
#pragma unroll
    for (int h = 0; h < 22; ++h) {
      float yv = wyp[h];
#pragma unroll
      for (int w = 0; w < 22; w += 2) {
        int k = h*22 + w;                       // even
        int s = k >> 6, j = (k >> 3) & 7, e = k & 7;
        unsigned idx = (unsigned)((s*144 + r)*64 + ((j ^ rx) << 3) + e);
        *(unsigned*)&outB[idx] = pk_bf16(yv * wxp[w], yv * wxp[w+1]);
      }
    }
#pragma unroll
    for (int k = 484; k < 512; k += 2) {
      int s = k >> 6, j = (k >> 3) & 7, e = k & 7;
      unsigned idx = (unsigned)((s*144 + r)*64 + ((j ^ rx) << 3) + e);
      *(unsigned*)&outB[idx] = 0u;
    }
  }
}

// ---------------- K1: fused fp32->bf16 for w1,w2,w3 (8 floats/thread)
__global__ __launch_bounds__(256) void cvt3_bf16(const float* __restrict__ w1, const float* __restrict__ w2,
                                                 const float* __restrict__ w3,
                                                 unsigned short* __restrict__ o1, unsigned short* __restrict__ o2,
                                                 unsigned short* __restrict__ o3) {
  int i = blockIdx.x * 256 + threadIdx.x;     // 131072 groups total
  const float* src; unsigned short* dst; int g;
  if (i < 65536)      { src = w1; dst = o1; g = i; }
  else if (i < 98304) { src = w2; dst = o2; g = i - 65536; }
  else                { src = w3; dst = o3; g = i - 98304; }
  float4 a = ((const float4*)src)[2*g];
  float4 b = ((const float4*)src)[2*g + 1];
  uint4 pk;
  pk.x = pk_bf16(a.x, a.y); pk.y = pk_bf16(a.z, a.w);
  pk.z = pk_bf16(b.x, b.y); pk.w = pk_bf16(b.z, b.w);
  ((uint4*)dst)[g] = pk;
}

// ---------------- K1b: conv_w [o][c][qp] fp32 -> Wfb[o][qp*1024 + c] bf16
__global__ __launch_bounds__(256) void convw_t(const float* __restrict__ cw,
                                               unsigned short* __restrict__ out) {
  __shared__ unsigned short T[9][1028];
  int o = blockIdx.x, tid = threadIdx.x;
  const float4* src = (const float4*)(cw + (size_t)o * 9216);
#pragma unroll
  for (int it = 0; it < 9; ++it) {
    int i = tid + it * 256;
    float4 v = src[i];
    int e = i * 4;
    { int c = e / 9,     qp = e - c*9;        T[qp][c] = (unsigned short)f2bf(v.x); }
    { int ee = e+1; int c = ee / 9, qp = ee - c*9; T[qp][c] = (unsigned short)f2bf(v.y); }
    { int ee = e+2; int c = ee / 9, qp = ee - c*9; T[qp][c] = (unsigned short)f2bf(v.z); }
    { int ee = e+3; int c = ee / 9, qp = ee - c*9; T[qp][c] = (unsigned short)f2bf(v.w); }
  }
  __syncthreads();
  unsigned short* dst = out + (size_t)o * 9216;
#pragma unroll
  for (int qp = 0; qp < 9; ++qp) {
    uint2 w = *(const uint2*)&T[qp][tid * 4];
    ((uint2*)(dst + qp * 1024))[tid] = w;
  }
}

// ---------------- K2: pooling GEMM. A via glds16 (dbuf, swizzled W2d), B reg-staged (T14).
// Block (nch, b); 384 thr = 6 waves (3wm x 2wn). M=144, N=64, K=512.
__global__ __launch_bounds__(384) void pool_gemm(const float* __restrict__ feat,
                                                 const unsigned short* __restrict__ W2d,
                                                 unsigned short* __restrict__ X) {
  __shared__ __align__(16) unsigned short Abuf[2][144*64];   // 2 x 18432 B
  __shared__ __align__(16) unsigned short Bs[64*72];         // 9216 B
  int tid = threadIdx.x;
  int nch = blockIdx.x, b = blockIdx.y;
  int lane = tid & 63, wid = tid >> 6;
  int wm = wid >> 1, wn = wid & 1;
  int l15 = lane & 15, kg = lane >> 4;
  const unsigned short* w2b = W2d + (size_t)b * 8 * 9216;
  const float* fb = feat + ((size_t)b * C_ + (size_t)nch * 64) * 484;
  f32x4 acc[3][2] = {};

  int c0 = tid >> 4,  f40 = tid & 15;
  int i1 = tid + 384; int c1 = i1 >> 4, f41 = i1 & 15;
  int i2 = tid + 768; bool has2 = i2 < 1024; int c2 = i2 >> 4, f42 = i2 & 15;
  float4 bR0, bR1, bR2;

#define LOADB(s) do { \
    bR0 = (((s) < 7 || f40 <= 8) ? *(const float4*)(fb + (size_t)c0*484 + (s)*64 + f40*4) : make_float4(0,0,0,0)); \
    bR1 = (((s) < 7 || f41 <= 8) ? *(const float4*)(fb + (size_t)c1*484 + (s)*64 + f41*4) : make_float4(0,0,0,0)); \
    if (has2) bR2 = (((s) < 7 || f42 <= 8) ? *(const float4*)(fb + (size_t)c2*484 + (s)*64 + f42*4) : make_float4(0,0,0,0)); \
  } while (0)

#define WRITEB() do { \
    uint2 p0; p0.x = pk_bf16(bR0.x, bR0.y); p0.y = pk_bf16(bR0.z, bR0.w); \
    *(uint2*)&Bs[c0*72 + f40*4] = p0; \
    uint2 p1; p1.x = pk_bf16(bR1.x, bR1.y); p1.y = pk_bf16(bR1.z, bR1.w); \
    *(uint2*)&Bs[c1*72 + f41*4] = p1; \
    if (has2) { uint2 p2; p2.x = pk_bf16(bR2.x, bR2.y); p2.y = pk_bf16(bR2.z, bR2.w); \
      *(uint2*)&Bs[c2*72 + f42*4] = p2; } \
  } while (0)

#define ISSUEA(buf, s) do { const unsigned short* sp_ = w2b + (size_t)(s) * 9216; \
    _Pragma("unroll") for (int ii = 0; ii < 3; ++ii) { \
      int slot_ = tid + ii * 384; \
      glds16(sp_ + slot_ * 8, (char*)&Abuf[(buf)][0] + (ii*384 + wid*64) * 16); } \
  } while (0)

  ISSUEA(0, 0);
  LOADB(0);
  WRITEB();                        // vmcnt-waits B regs once
  int cur = 0;
#pragma unroll
  for (int s = 0; s < 8; ++s) {
    __syncthreads();               // A(s) glds drained; B(s) visible
    if (s < 7) { ISSUEA(cur ^ 1, s + 1); LOADB(s + 1); }

    bf16x8 af[3][2], bf[2][2];
#pragma unroll
    for (int fm = 0; fm < 3; ++fm)
#pragma unroll
      for (int kk = 0; kk < 2; ++kk) {
        int row = wm*48 + fm*16 + l15;
        af[fm][kk] = *(const bf16x8*)&Abuf[cur][row*64 + (((kk*4 + kg) ^ (l15 & 7)) << 3)];
      }
#pragma unroll
    for (int fn = 0; fn < 2; ++fn)
#pragma unroll
      for (int kk = 0; kk < 2; ++kk)
        bf[fn][kk] = *(const bf16x8*)&Bs[(wn*32 + fn*16 + l15) * 72 + kk*32 + kg*8];
#pragma unroll
    for (int fm = 0; fm < 3; ++fm)
#pragma unroll
      for (int fn = 0; fn < 2; ++fn) {
        acc[fm][fn] = __builtin_amdgcn_mfma_f32_16x16x32_bf16(af[fm][0], bf[fn][0], acc[fm][fn], 0, 0, 0);
        acc[fm][fn] = __builtin_amdgcn_mfma_f32_16x16x32_bf16(af[fm][1], bf[fn][1], acc[fm][fn], 0, 0, 0);
      }
    __syncthreads();               // Bs reads complete
    if (s < 7) WRITEB();           // vmcnt covered by compute
    cur ^= 1;
  }
#undef LOADB
#undef WRITEB
#undef ISSUEA

#pragma unroll
  for (int fm = 0; fm < 3; ++fm)
#pragma unroll
    for (int r = 0; r < 4; ++r) {
      int m = wm*48 + fm*16 + kg*4 + r;
      int n = m / 9, qp = m - n*9;
      size_t base = ((size_t)(b*16 + n)) * KCONV + (size_t)qp * 1024 + (size_t)nch * 64;
#pragma unroll
      for (int fn = 0; fn < 2; ++fn)
        X[base + wn*32 + fn*16 + l15] = (unsigned short)f2bf(acc[fm][fn][r]);
    }
}

// ---------------- K3: 128x128 NT GEMM + fused split-K reduction & BN/ReLU epilogue (MODE 0).
__global__ __launch_bounds__(256) void gemm128f(const unsigned short* __restrict__ A,
                                                const unsigned short* __restrict__ Bm,
                                                float* __restrict__ Cp, unsigned* __restrict__ ctr,
                                                int M, int N, int K, int kChunk, int SK,
                                                const float* __restrict__ bias,
                                                const float* __restrict__ g,
                                                const float* __restrict__ be,
                                                const float* __restrict__ mu,
                                                const float* __restrict__ var,
                                                unsigned short* __restrict__ outb) {
  __shared__ __align__(16) unsigned short As[2][4096];
  __shared__ __align__(16) unsigned short Bs[2][4096];
  __shared__ unsigned lastflag;
  int tid = threadIdx.x;
  int lane = tid & 63, wid = tid >> 6;
  int wm = wid >> 1, wn = wid & 1;
  int l15 = lane & 15, kg = lane >> 4;
  int nt = blockIdx.x, mt = blockIdx.y, z = blockIdx.z;
  int kbeg = z * kChunk;
  int steps = kChunk / 32;

  int row0 = tid >> 2, row1 = 64 + row0;
  int slot = tid & 3;
  int s0 = slot ^ ((row0 >> 1) & 3);
  int s1 = slot ^ ((row1 >> 1) & 3);
  const unsigned short* ga0 = A  + (size_t)(mt*128 + row0) * K + kbeg + s0*8;
  const unsigned short* ga1 = A  + (size_t)(mt*128 + row1) * K + kbeg + s1*8;
  const unsigned short* gb0 = Bm + (size_t)(nt*128 + row0) * K + kbeg + s0*8;
  const unsigned short* gb1 = Bm + (size_t)(nt*128 + row1) * K + kbeg + s1*8;
  int wbyte = wid * 1024;

  f32x4 acc[4][4] = {};
  int cur = 0;

#define ISSUE(buf, s) do { int ko = (s) * 32; \
    glds16(ga0 + ko, (char*)&As[(buf)][0] + wbyte); \
    glds16(ga1 + ko, (char*)&As[(buf)][0] + 4096 + wbyte); \
    glds16(gb0 + ko, (char*)&Bs[(buf)][0] + wbyte); \
    glds16(gb1 + ko, (char*)&Bs[(buf)][0] + 4096 + wbyte); } while (0)

  ISSUE(0, 0);
  for (int s = 0; s < steps; ++s) {
    __syncthreads();
    if (s + 1 < steps) ISSUE(cur ^ 1, s + 1);
    bf16x8 af[4], bfr[4];
#pragma unroll
    for (int fm = 0; fm < 4; ++fm) {
      int fr = wm*64 + fm*16 + l15;
      af[fm] = *(const bf16x8*)&As[cur][fr*32 + ((kg ^ ((fr >> 1) & 3)) << 3)];
    }
#pragma unroll
    for (int fn = 0; fn < 4; ++fn) {
      int fr = wn*64 + fn*16 + l15;
      bfr[fn] = *(const bf16x8*)&Bs[cur][fr*32 + ((kg ^ ((fr >> 1) & 3)) << 3)];
    }
#pragma unroll
    for (int fm = 0; fm < 4; ++fm)
#pragma unroll
      for (int fn = 0; fn < 4; ++fn)
        acc[fm][fn] = __builtin_amdgcn_mfma_f32_16x16x32_bf16(af[fm], bfr[fn], acc[fm][fn], 0, 0, 0);
    cur ^= 1;
  }
#undef ISSUE

  float* cp = Cp + ((size_t)z * M + (size_t)mt * 128) * N + (size_t)nt * 128;
#pragma unroll
  for (int fm = 0; fm < 4; ++fm)
#pragma unroll
    for (int fn = 0; fn < 4; ++fn)
#pragma unroll
      for (int r = 0; r < 4; ++r) {
        int row = wm*64 + fm*16 + kg*4 + r;
        int col = wn*64 + fn*16 + l15;
        cp[(size_t)row * N + col] = acc[fm][fn][r];
      }

  __threadfence();
  __syncthreads();
  if (tid == 0) lastflag = (atomicAdd(&ctr[mt * (N >> 7) + nt], 1u) == (unsigned)(SK - 1));
  __syncthreads();
  if (!lastflag) return;
  __threadfence();

  const float* base0 = Cp + ((size_t)mt * 128) * N + (size_t)nt * 128;
  size_t zs = (size_t)M * N;
#pragma unroll
  for (int fn = 0; fn < 4; ++fn) {
    int col = wn*64 + fn*16 + l15;
    int cg = nt*128 + col;
    float sc = g[cg] * rsqrtf(var[cg] + EPS_);
    float bi = bias[cg] - mu[cg], bt = be[cg];
#pragma unroll
    for (int fm = 0; fm < 4; ++fm)
#pragma unroll
      for (int r = 0; r < 4; ++r) {
        int row = wm*64 + fm*16 + kg*4 + r;
        const float* p = base0 + (size_t)row * N + col;
        float ssum = 0.f;
        for (int z2 = 0; z2 < SK; ++z2) ssum += p[z2 * zs];
        float t = fmaxf((ssum + bi) * sc + bt, 0.f);
        outb[(size_t)(mt*128 + row) * N + cg] = (unsigned short)f2bf(t);
      }
  }
}

// ---------------- K3b: 64x64 NT GEMM + fused split-K reduction & epilogue.
// MODE 1: bias+ReLU -> bf16 ; MODE 2: bias -> fp32
template<int MODE>
__global__ __launch_bounds__(256) void gemm_ntf(const unsigned short* __restrict__ A,
                                                const unsigned short* __restrict__ Bm,
                                                float* __restrict__ Cp, unsigned* __restrict__ ctr,
                                                int M, int N, int K, int kChunk, int SK,
                                                const float* __restrict__ bias,
                                                unsigned short* __restrict__ outb,
                                                float* __restrict__ outf) {
  __shared__ __align__(16) unsigned short As[64][40];
  __shared__ __align__(16) unsigned short Bs[64][40];
  __shared__ unsigned lastflag;
  int tid = threadIdx.x;
  int lane = tid & 63, wid = tid >> 6;
  int wm = wid >> 1, wn = wid & 1;
  int l15 = lane & 15, kg = lane >> 4;
  int nt = blockIdx.x, mt = blockIdx.y, z = blockIdx.z;
  int kbeg = z * kChunk;
  int kend = kbeg + kChunk;
  int srow = tid >> 2, sseg = tid & 3;
  const unsigned short* aG = A  + (size_t)(mt*64 + srow) * K + sseg * 8;
  const unsigned short* bG = Bm + (size_t)(nt*64 + srow) * K + sseg * 8;
  f32x4 acc[2][2] = {};

  for (int k0 = kbeg; k0 < kend; k0 += 32) {
    uint4 av = *(const uint4*)(aG + k0);
    uint4 bv = *(const uint4*)(bG + k0);
    __syncthreads();
    *(uint4*)&As[srow][sseg*8] = av;
    *(uint4*)&Bs[srow][sseg*8] = bv;
    __syncthreads();
    bf16x8 a0 = *(const bf16x8*)&As[wm*32 +      l15][kg*8];
    bf16x8 a1 = *(const bf16x8*)&As[wm*32 + 16 + l15][kg*8];
    bf16x8 b0 = *(const bf16x8*)&Bs[wn*32 +      l15][kg*8];
    bf16x8 b1 = *(const bf16x8*)&Bs[wn*32 + 16 + l15][kg*8];
    acc[0][0] = __builtin_amdgcn_mfma_f32_16x16x32_bf16(a0, b0, acc[0][0], 0, 0, 0);
    acc[0][1] = __builtin_amdgcn_mfma_f32_16x16x32_bf16(a0, b1, acc[0][1], 0, 0, 0);
    acc[1][0] = __builtin_amdgcn_mfma_f32_16x16x32_bf16(a1, b0, acc[1][0], 0, 0, 0);
    acc[1][1] = __builtin_amdgcn_mfma_f32_16x16x32_bf16(a1, b1, acc[1][1], 0, 0, 0);
  }

  float* cp = Cp + ((size_t)z * M + (size_t)mt * 64) * N + (size_t)nt * 64;
#pragma unroll
  for (int fm = 0; fm < 2; ++fm)
#pragma unroll
    for (int fn = 0; fn < 2; ++fn)
#pragma unroll
      for (int r = 0; r < 4; ++r) {
        int row = wm*32 + fm*16 + kg*4 + r;
        int col = wn*32 + fn*16 + l15;
        cp[(size_t)row * N + col] = acc[fm][fn][r];
      }

  __threadfence();
  __syncthreads();
  if (tid == 0) lastflag = (atomicAdd(&ctr[mt * (N >> 6) + nt], 1u) == (unsigned)(SK - 1));
  __syncthreads();
  if (!lastflag) return;
  __threadfence();

  const float* base0 = Cp + ((size_t)mt * 64) * N + (size_t)nt * 64;
  size_t zs = (size_t)M * N;
#pragma unroll
  for (int fn = 0; fn < 2; ++fn) {
    int col = wn*32 + fn*16 + l15;
    int cg = nt*64 + col;
    float bi = bias[cg];
#pragma unroll
    for (int fm = 0; fm < 2; ++fm)
#pragma unroll
      for (int r = 0; r < 4; ++r) {
        int row = wm*32 + fm*16 + kg*4 + r;
        const float* p = base0 + (size_t)row * N + col;
        float ssum = 0.f;
        for (int z2 = 0; z2 < SK; ++z2) ssum += p[z2 * zs];
        if (MODE == 1)
          outb[(size_t)(mt*64 + row) * N + cg] = (unsigned short)f2bf(fmaxf(ssum + bi, 0.f));
        else
          outf[(size_t)(mt*64 + row) * N + cg] = ssum + bi;
      }
  }
}

extern "C" void kernel_launch(void* const* d_in, const int* in_sizes, int n_in,
                              void* d_out, int out_size, void* d_ws, size_t ws_size,
                              hipStream_t stream) {
  const float* feat   = (const float*)d_in[0];
  const float* bbox   = (const float*)d_in[1];
  const float* conv_w = (const float*)d_in[2];
  const float* conv_b = (const float*)d_in[3];
  const float* gamma  = (const float*)d_in[4];
  const float* beta   = (const float*)d_in[5];
  const float* mean   = (const float*)d_in[6];
  const float* var    = (const float*)d_in[7];
  const float* w1     = (const float*)d_in[8];
  const float* b1     = (const float*)d_in[9];
  const float* w2     = (const float*)d_in[10];
  const float* b2     = (const float*)d_in[11];
  const float* w3     = (const float*)d_in[12];
  const float* b3     = (const float*)d_in[13];

  char* ws = (char*)d_ws;
  unsigned short* W2d = (unsigned short*)(ws);              //  4718592 B [32][8][144][64]
  unsigned short* Xb  = (unsigned short*)(ws + 4718592);    //  9437184 B [512][9216]
  unsigned short* Wfb = (unsigned short*)(ws + 14155776);   // 18874368 B [1024][9216]
  unsigned short* w1b = (unsigned short*)(ws + 33030144);   //  1048576 B
  unsigned short* w2b = (unsigned short*)(ws + 34078720);   //   524288 B
  unsigned short* w3b = (unsigned short*)(ws + 34603008);   //   524288 B
  float*          part= (float*)(ws + 35127296);            // 33554432 B [16][512][1024] f32
  unsigned short* H0  = (unsigned short*)(ws + 68681728);   //  1048576 B
  unsigned short* H1  = (unsigned short*)(ws + 69730304);   //   524288 B
  unsigned short* H2  = (unsigned short*)(ws + 70254592);   //   524288 B
  unsigned*       ctr = (unsigned*)(ws + 70778880);         //     1024 B (total 70779904 B)

  prep_w2d<<<32, 192, 0, stream>>>(bbox, W2d, ctr);
  convw_t<<<1024, 256, 0, stream>>>(conv_w, Wfb);
  cvt3_bf16<<<512, 256, 0, stream>>>(w1, w2, w3, w1b, w2b, w3b);

  // pooling GEMM: per-b, M=144, N=1024 (16 chunks of 64), K=512
  pool_gemm<<<dim3(16, 32), 384, 0, stream>>>(feat, W2d, Xb);

  // conv GEMM: [512,9216] x [1024,9216]^T, 128^2 tiles, SK=16 -> 512 blocks, fused BN+ReLU
  gemm128f<<<dim3(8, 4, 16), 256, 0, stream>>>(Xb, Wfb, part, ctr, 512, 1024, 9216, 576, 16,
      conv_b, gamma, beta, mean, var, H0);

  // MLP1: [512,1024] x [512,1024]^T, SK=8, fused bias+ReLU
  gemm_ntf<1><<<dim3(8, 8, 8), 256, 0, stream>>>(H0, w1b, part, ctr + 32, 512, 512, 1024, 128, 8,
      b1, H1, nullptr);
  // MLP2: [512,512] x [512,512]^T, SK=8, fused bias+ReLU
  gemm_ntf<1><<<dim3(8, 8, 8), 256, 0, stream>>>(H1, w2b, part, ctr + 96, 512, 512, 512, 64, 8,
      b2, H2, nullptr);
  // MLP3: [512,512] x [512,512]^T, SK=8, fused bias -> fp32 out
  gemm_ntf<2><<<dim3(8, 8, 8), 256, 0, stream>>>(H2, w3b, part, ctr + 160, 512, 512, 512, 64, 8,
      b3, nullptr, (float*)d_out);
}

// Round 6
// 130.468 us; speedup vs baseline: 4.8656x; 4.8656x over previous
//
#include <hip/hip_runtime.h>
#include <hip/hip_bf16.h>

#define B_    32
#define NBB_  16
#define C_    1024
#define NROI  512
#define KCONV 9216
#define SCALE_ (1.0f/16.0f)
#define EPS_  1e-5f

using f32x4  = __attribute__((ext_vector_type(4))) float;
using bf16x8 = __attribute__((ext_vector_type(8))) short;

__device__ __forceinline__ unsigned f2bf(float f) {
  union { float f; unsigned u; } x; x.f = f;
  unsigned r = x.u + 0x7fffu + ((x.u >> 16) & 1u);   // RNE
  return r >> 16;
}

__device__ __forceinline__ unsigned pk_bf16(float lo, float hi) {
  __hip_bfloat162 h = __float22bfloat162_rn(make_float2(lo, hi));
  return *reinterpret_cast<unsigned*>(&h);
}

__device__ __forceinline__ float hat_int(float t) {
  t = fminf(fmaxf(t, -1.f), 1.f);
  return t + 0.5f - 0.5f * t * fabsf(t);
}

__device__ __forceinline__ void glds16(const void* g, void* l) {
  __builtin_amdgcn_global_load_lds((const __attribute__((address_space(1))) void*)g,
                                   (__attribute__((address_space(3))) void*)l, 16, 0, 0);
}

// ---------------- K0: fused ROI weights + W2d build (plain [b][144][512] bf16, k-linear).
__global__ __launch_bounds__(192) void prep_w2d(const float* __restrict__ bbox,
                                                unsigned short* __restrict__ W2d) {
  __shared__ float wyS[16*66], wxS[16*66];
  int b = blockIdx.x, tid = threadIdx.x;
  for (int t = tid; t < 352; t += 192) {
    int n = t / 22, i = t - n * 22;
    float4 bb = ((const float4*)bbox)[b*16 + n];
    float x1 = bb.x * SCALE_, y1 = bb.y * SCALE_;
    float x2 = (bb.x + bb.z) * SCALE_, y2 = (bb.y + bb.w) * SCALE_;
    float bw = (x2 - x1) / 3.f, bh = (y2 - y1) / 3.f;
    float area = fmaxf(bw * bh, 0.f);
    float inv = area > 0.f ? 1.f / fmaxf(area, 1e-12f) : 0.f;
    float fi = (float)i;
#pragma unroll
    for (int q = 0; q < 3; ++q) {
      float sy = y1 + q * bh;
      wyS[n*66 + q*22 + i] = hat_int(sy + bh - fi) - hat_int(sy - fi);
      float sx = x1 + q * bw;
      wxS[n*66 + q*22 + i] = (hat_int(sx + bw - fi) - hat_int(sx - fi)) * inv;
    }
  }
  __syncthreads();
  if (tid < 144) {
    int n = tid / 9, qp = tid - n*9, q = qp / 3, p = qp - q*3;
    const float* wyp = wyS + n*66 + q*22;
    const float* wxp = wxS + n*66 + p*22;
    unsigned short* out = W2d + ((size_t)b*144 + tid) * 512;
    for (int h = 0; h < 22; ++h) {
      float yv = wyp[h];
      int kb = h * 22;
#pragma unroll
      for (int w = 0; w < 22; w += 2)
        *(unsigned*)&out[kb + w] = pk_bf16(yv * wxp[w], yv * wxp[w+1]);
    }
#pragma unroll
    for (int k = 484; k < 512; k += 2) *(unsigned*)&out[k] = 0u;
  }
}

// ---------------- K1: fused fp32->bf16 for w1,w2,w3
__global__ __launch_bounds__(256) void cvt3_bf16(const float* __restrict__ w1, const float* __restrict__ w2,
                                                 const float* __restrict__ w3,
                                                 unsigned short* __restrict__ o1, unsigned short* __restrict__ o2,
                                                 unsigned short* __restrict__ o3) {
  int i = blockIdx.x * 256 + threadIdx.x;
  const float* src; unsigned short* dst; int g;
  if (i < 65536)      { src = w1; dst = o1; g = i; }
  else if (i < 98304) { src = w2; dst = o2; g = i - 65536; }
  else                { src = w3; dst = o3; g = i - 98304; }
  float4 a = ((const float4*)src)[2*g];
  float4 b = ((const float4*)src)[2*g + 1];
  uint4 pk;
  pk.x = pk_bf16(a.x, a.y); pk.y = pk_bf16(a.z, a.w);
  pk.z = pk_bf16(b.x, b.y); pk.w = pk_bf16(b.z, b.w);
  ((uint4*)dst)[g] = pk;
}

// ---------------- K1b: conv_w [o][c][qp] fp32 -> Wfb[o][qp*1024 + c] bf16
__global__ __launch_bounds__(256) void convw_t(const float* __restrict__ cw,
                                               unsigned short* __restrict__ out) {
  __shared__ unsigned short T[9][1028];
  int o = blockIdx.x, tid = threadIdx.x;
  const float4* src = (const float4*)(cw + (size_t)o * 9216);
#pragma unroll
  for (int it = 0; it < 9; ++it) {
    int i = tid + it * 256;
    float4 v = src[i];
    int e = i * 4;
    { int c = e / 9,     qp = e - c*9;             T[qp][c] = (unsigned short)f2bf(v.x); }
    { int ee = e+1; int c = ee / 9, qp = ee - c*9; T[qp][c] = (unsigned short)f2bf(v.y); }
    { int ee = e+2; int c = ee / 9, qp = ee - c*9; T[qp][c] = (unsigned short)f2bf(v.z); }
    { int ee = e+3; int c = ee / 9, qp = ee - c*9; T[qp][c] = (unsigned short)f2bf(v.w); }
  }
  __syncthreads();
  unsigned short* dst = out + (size_t)o * 9216;
#pragma unroll
  for (int qp = 0; qp < 9; ++qp) {
    uint2 w = *(const uint2*)&T[qp][tid * 4];
    ((uint2*)(dst + qp * 1024))[tid] = w;
  }
}

// ---------------- K1c: feat fp32 -> featB[b][c][512pad] bf16 (pure stream, no transpose)
__global__ __launch_bounds__(256) void cvt_feat(const float* __restrict__ feat,
                                                unsigned short* __restrict__ featB) {
  int blk = blockIdx.x;                       // 2048 = (32*1024)/16 channel-groups
  int tid = threadIdx.x;
  const float4* src = (const float4*)(feat + (size_t)blk * 16 * 484);
  unsigned short* dstB = featB + (size_t)blk * 16 * 512;
#pragma unroll
  for (int it = 0; it < 8; ++it) {
    int j = tid + it * 256;                   // 1936 float4 total
    if (j < 1936) {
      float4 v = src[j];
      int lin = j * 4;
      int c = lin / 484, w = lin - c * 484;
      uint2 pk;
      pk.x = pk_bf16(v.x, v.y); pk.y = pk_bf16(v.z, v.w);
      *(uint2*)&dstB[(size_t)c * 512 + w] = pk;
    }
  }
  if (tid < 112) {                            // zero pad k = 484..511 for 16 channels
    int c = tid / 7, ws = tid - c * 7;
    uint2 z; z.x = 0u; z.y = 0u;
    *(uint2*)&dstB[(size_t)c * 512 + 484 + ws * 4] = z;
  }
}

// ---------------- K2: pooling GEMM, gemm128-style. Per b: X = W2d[b](144x512) . featB[b](1024x512)^T
// Block (nt: 128-ch tile, b); 384 thr = 6 waves (3wm x 2wn). glds16 + dbuf + src-side XOR swizzle.
__global__ __launch_bounds__(384) void pool_gemm(const unsigned short* __restrict__ W2d,
                                                 const unsigned short* __restrict__ featB,
                                                 unsigned short* __restrict__ X) {
  __shared__ __align__(16) unsigned short As[2][4608];   // 144 rows x 32 bf16
  __shared__ __align__(16) unsigned short Bs[2][4096];   // 128 rows x 32 bf16
  int tid = threadIdx.x;
  int nt = blockIdx.x, b = blockIdx.y;
  int lane = tid & 63, wid = tid >> 6;
  int wm = wid >> 1, wn = wid & 1;             // wm 0..2 (48 rows), wn 0..1 (64 cols)
  int l15 = lane & 15, kg = lane >> 4;
  const unsigned short* aBase = W2d  + (size_t)b * 144 * 512;
  const unsigned short* bBase = featB + ((size_t)b * 1024 + (size_t)nt * 128) * 512;
  f32x4 acc[3][4] = {};

  // staging: 1088 16B slots (A: 576 = 144x4, B: 512 = 128x4); 3 issues x 6 waves x 64 lanes
  // boundaries align: issue1 wid<3 -> A, wid>=3 -> B; issue2 wid<5 -> B, wid5 skip.
#define ISSUEP(buf, s) do { int k0_ = (s) * 32; \
    _Pragma("unroll") for (int ii = 0; ii < 3; ++ii) { \
      int sb = ii*384 + wid*64; \
      if (sb < 1088) { \
        int slot = sb + lane; \
        if (sb < 576) { \
          int row = slot >> 2, seg = (slot & 3) ^ ((row >> 1) & 3); \
          glds16(aBase + (size_t)row*512 + k0_ + seg*8, (char*)&As[(buf)][0] + sb*16); \
        } else { \
          int s2 = slot - 576; int row = s2 >> 2, seg = (s2 & 3) ^ ((row >> 1) & 3); \
          glds16(bBase + (size_t)row*512 + k0_ + seg*8, (char*)&Bs[(buf)][0] + (sb-576)*16); \
        } } } } while (0)

  ISSUEP(0, 0);
  int cur = 0;
  for (int s = 0; s < 16; ++s) {
    __syncthreads();                           // buf[cur] staged (sync drains vmcnt), prev reads done
    if (s < 15) ISSUEP(cur ^ 1, s + 1);
    bf16x8 af[3], bfr[4];
#pragma unroll
    for (int fm = 0; fm < 3; ++fm) {
      int r = wm*48 + fm*16 + l15;
      af[fm] = *(const bf16x8*)&As[cur][r*32 + ((kg ^ ((r >> 1) & 3)) << 3)];
    }
#pragma unroll
    for (int fn = 0; fn < 4; ++fn) {
      int r = wn*64 + fn*16 + l15;
      bfr[fn] = *(const bf16x8*)&Bs[cur][r*32 + ((kg ^ ((r >> 1) & 3)) << 3)];
    }
#pragma unroll
    for (int fm = 0; fm < 3; ++fm)
#pragma unroll
      for (int fn = 0; fn < 4; ++fn)
        acc[fm][fn] = __builtin_amdgcn_mfma_f32_16x16x32_bf16(af[fm], bfr[fn], acc[fm][fn], 0, 0, 0);
    cur ^= 1;
  }
#undef ISSUEP

  // C-write: row m=(n,qp) -> X[b*16+n][qp*1024 + channel], channel = nt*128 + wn*64 + fn*16 + l15
#pragma unroll
  for (int fm = 0; fm < 3; ++fm)
#pragma unroll
    for (int r = 0; r < 4; ++r) {
      int m = wm*48 + fm*16 + kg*4 + r;
      int n = m / 9, qp = m - n*9;
      size_t base = ((size_t)(b*16 + n)) * KCONV + (size_t)qp * 1024 + (size_t)nt * 128;
#pragma unroll
      for (int fn = 0; fn < 4; ++fn)
        X[base + wn*64 + fn*16 + l15] = (unsigned short)f2bf(acc[fm][fn][r]);
    }
}

// ---------------- K3: 128x128 NT GEMM, glds16 + dbuf + XOR swizzle, split-K partials.
__global__ __launch_bounds__(256) void gemm128(const unsigned short* __restrict__ A,
                                               const unsigned short* __restrict__ Bm,
                                               float* __restrict__ Cp,
                                               int M, int N, int K, int kChunk) {
  __shared__ __align__(16) unsigned short As[2][4096];
  __shared__ __align__(16) unsigned short Bs[2][4096];
  int tid = threadIdx.x;
  int lane = tid & 63, wid = tid >> 6;
  int wm = wid >> 1, wn = wid & 1;
  int l15 = lane & 15, kg = lane >> 4;
  int nt = blockIdx.x, mt = blockIdx.y, z = blockIdx.z;
  int kbeg = z * kChunk;
  int steps = kChunk / 32;

  int row0 = tid >> 2, row1 = 64 + row0;
  int slot = tid & 3;
  int s0 = slot ^ ((row0 >> 1) & 3);
  int s1 = slot ^ ((row1 >> 1) & 3);
  const unsigned short* ga0 = A  + (size_t)(mt*128 + row0) * K + kbeg + s0*8;
  const unsigned short* ga1 = A  + (size_t)(mt*128 + row1) * K + kbeg + s1*8;
  const unsigned short* gb0 = Bm + (size_t)(nt*128 + row0) * K + kbeg + s0*8;
  const unsigned short* gb1 = Bm + (size_t)(nt*128 + row1) * K + kbeg + s1*8;
  int wbyte = wid * 1024;

  f32x4 acc[4][4] = {};
  int cur = 0;

#define ISSUE(buf, s) do { int ko = (s) * 32; \
    glds16(ga0 + ko, (char*)&As[(buf)][0] + wbyte); \
    glds16(ga1 + ko, (char*)&As[(buf)][0] + 4096 + wbyte); \
    glds16(gb0 + ko, (char*)&Bs[(buf)][0] + wbyte); \
    glds16(gb1 + ko, (char*)&Bs[(buf)][0] + 4096 + wbyte); } while (0)

  ISSUE(0, 0);
  for (int s = 0; s < steps; ++s) {
    __syncthreads();
    if (s + 1 < steps) ISSUE(cur ^ 1, s + 1);
    bf16x8 af[4], bfr[4];
#pragma unroll
    for (int fm = 0; fm < 4; ++fm) {
      int fr = wm*64 + fm*16 + l15;
      af[fm] = *(const bf16x8*)&As[cur][fr*32 + ((kg ^ ((fr >> 1) & 3)) << 3)];
    }
#pragma unroll
    for (int fn = 0; fn < 4; ++fn) {
      int fr = wn*64 + fn*16 + l15;
      bfr[fn] = *(const bf16x8*)&Bs[cur][fr*32 + ((kg ^ ((fr >> 1) & 3)) << 3)];
    }
#pragma unroll
    for (int fm = 0; fm < 4; ++fm)
#pragma unroll
      for (int fn = 0; fn < 4; ++fn)
        acc[fm][fn] = __builtin_amdgcn_mfma_f32_16x16x32_bf16(af[fm], bfr[fn], acc[fm][fn], 0, 0, 0);
    cur ^= 1;
  }
#undef ISSUE

  float* cp = Cp + ((size_t)z * M + (size_t)mt * 128) * N + (size_t)nt * 128;
#pragma unroll
  for (int fm = 0; fm < 4; ++fm)
#pragma unroll
    for (int fn = 0; fn < 4; ++fn)
#pragma unroll
      for (int r = 0; r < 4; ++r) {
        int row = wm*64 + fm*16 + kg*4 + r;
        int col = wn*64 + fn*16 + l15;
        cp[(size_t)row * N + col] = acc[fm][fn][r];
      }
}

// ---------------- K3b: 64x64 NT GEMM (MLP sizes), split-K partials
__global__ __launch_bounds__(256) void gemm_nt(const unsigned short* __restrict__ A,
                                               const unsigned short* __restrict__ Bm,
                                               float* __restrict__ Cp,
                                               int M, int N, int K, int kChunk) {
  __shared__ __align__(16) unsigned short As[64][40];
  __shared__ __align__(16) unsigned short Bs[64][40];
  int tid = threadIdx.x;
  int lane = tid & 63, wid = tid >> 6;
  int wm = wid >> 1, wn = wid & 1;
  int l15 = lane & 15, kg = lane >> 4;
  int nt = blockIdx.x, mt = blockIdx.y, z = blockIdx.z;
  int kbeg = z * kChunk;
  int kend = kbeg + kChunk; if (kend > K) kend = K;
  int srow = tid >> 2, sseg = tid & 3;
  const unsigned short* aG = A  + (size_t)(mt*64 + srow) * K + sseg * 8;
  const unsigned short* bG = Bm + (size_t)(nt*64 + srow) * K + sseg * 8;
  f32x4 acc[2][2] = {};

  for (int k0 = kbeg; k0 < kend; k0 += 32) {
    uint4 av = *(const uint4*)(aG + k0);
    uint4 bv = *(const uint4*)(bG + k0);
    __syncthreads();
    *(uint4*)&As[srow][sseg*8] = av;
    *(uint4*)&Bs[srow][sseg*8] = bv;
    __syncthreads();
    bf16x8 a0 = *(const bf16x8*)&As[wm*32 +      l15][kg*8];
    bf16x8 a1 = *(const bf16x8*)&As[wm*32 + 16 + l15][kg*8];
    bf16x8 b0 = *(const bf16x8*)&Bs[wn*32 +      l15][kg*8];
    bf16x8 b1 = *(const bf16x8*)&Bs[wn*32 + 16 + l15][kg*8];
    acc[0][0] = __builtin_amdgcn_mfma_f32_16x16x32_bf16(a0, b0, acc[0][0], 0, 0, 0);
    acc[0][1] = __builtin_amdgcn_mfma_f32_16x16x32_bf16(a0, b1, acc[0][1], 0, 0, 0);
    acc[1][0] = __builtin_amdgcn_mfma_f32_16x16x32_bf16(a1, b0, acc[1][0], 0, 0, 0);
    acc[1][1] = __builtin_amdgcn_mfma_f32_16x16x32_bf16(a1, b1, acc[1][1], 0, 0, 0);
  }

  float* cp = Cp + ((size_t)z * M + (size_t)mt * 64) * N + (size_t)nt * 64;
#pragma unroll
  for (int fm = 0; fm < 2; ++fm)
#pragma unroll
    for (int fn = 0; fn < 2; ++fn)
#pragma unroll
      for (int r = 0; r < 4; ++r) {
        int row = wm*32 + fm*16 + kg*4 + r;
        int col = wn*32 + fn*16 + l15;
        cp[(size_t)row * N + col] = acc[fm][fn][r];
      }
}

// ---------------- K4: split-K reduce + epilogue (parallel, separate kernel — R4-proven)
template<int MODE>
__global__ __launch_bounds__(256) void epi(const float* __restrict__ Cp, int SK, int MN4, int N,
                                           const float* __restrict__ bias,
                                           const float* __restrict__ g,
                                           const float* __restrict__ be,
                                           const float* __restrict__ mu,
                                           const float* __restrict__ var,
                                           unsigned short* __restrict__ outb,
                                           float* __restrict__ outf) {
  int i = blockIdx.x * 256 + threadIdx.x;
  if (i >= MN4) return;
  float4 s = ((const float4*)Cp)[i];
  for (int z = 1; z < SK; ++z) {
    float4 t = ((const float4*)Cp)[(size_t)z * MN4 + i];
    s.x += t.x; s.y += t.y; s.z += t.z; s.w += t.w;
  }
  int n0 = (i * 4) % N;
  float v[4] = {s.x, s.y, s.z, s.w};
  if (MODE == 0) {
    float o[4];
#pragma unroll
    for (int j = 0; j < 4; ++j) {
      int n = n0 + j;
      float sc = g[n] * rsqrtf(var[n] + EPS_);
      o[j] = fmaxf((v[j] + bias[n] - mu[n]) * sc + be[n], 0.f);
    }
    uint2 pk; pk.x = pk_bf16(o[0], o[1]); pk.y = pk_bf16(o[2], o[3]);
    *(uint2*)&outb[(size_t)i * 4] = pk;
  } else if (MODE == 1) {
    uint2 pk;
    pk.x = pk_bf16(fmaxf(v[0] + bias[n0], 0.f),   fmaxf(v[1] + bias[n0+1], 0.f));
    pk.y = pk_bf16(fmaxf(v[2] + bias[n0+2], 0.f), fmaxf(v[3] + bias[n0+3], 0.f));
    *(uint2*)&outb[(size_t)i * 4] = pk;
  } else {
    float4 o;
    o.x = v[0] + bias[n0];     o.y = v[1] + bias[n0 + 1];
    o.z = v[2] + bias[n0 + 2]; o.w = v[3] + bias[n0 + 3];
    ((float4*)outf)[i] = o;
  }
}

extern "C" void kernel_launch(void* const* d_in, const int* in_sizes, int n_in,
                              void* d_out, int out_size, void* d_ws, size_t ws_size,
                              hipStream_t stream) {
  const float* feat   = (const float*)d_in[0];
  const float* bbox   = (const float*)d_in[1];
  const float* conv_w = (const float*)d_in[2];
  const float* conv_b = (const float*)d_in[3];
  const float* gamma  = (const float*)d_in[4];
  const float* beta   = (const float*)d_in[5];
  const float* mean   = (const float*)d_in[6];
  const float* var    = (const float*)d_in[7];
  const float* w1     = (const float*)d_in[8];
  const float* b1     = (const float*)d_in[9];
  const float* w2     = (const float*)d_in[10];
  const float* b2     = (const float*)d_in[11];
  const float* w3     = (const float*)d_in[12];
  const float* b3     = (const float*)d_in[13];

  char* ws = (char*)d_ws;
  // region A [0, 38273024): W2d + featB — dead after pool_gemm; part/H* overlay it.
  unsigned short* W2d  = (unsigned short*)(ws);              //  4718592 B [32][144][512]
  unsigned short* featB= (unsigned short*)(ws + 4718592);    // 33554432 B [32][1024][512]
  float*          part = (float*)(ws);                       // 16777216 B (overlay, SK<=8 of 512x1024)
  unsigned short* H0   = (unsigned short*)(ws + 16777216);   //  1048576 B (overlay)
  unsigned short* H1   = (unsigned short*)(ws + 17825792);   //   524288 B (overlay)
  unsigned short* H2   = (unsigned short*)(ws + 18350080);   //   524288 B (overlay)
  unsigned short* Xb   = (unsigned short*)(ws + 38273024);   //  9437184 B [512][9216]
  unsigned short* Wfb  = (unsigned short*)(ws + 47710208);   // 18874368 B [1024][9216]
  unsigned short* w1b  = (unsigned short*)(ws + 66584576);   //  1048576 B
  unsigned short* w2b  = (unsigned short*)(ws + 67633152);   //   524288 B
  unsigned short* w3b  = (unsigned short*)(ws + 68157440);   //   524288 B  (total 68681728 B)

  prep_w2d<<<32, 192, 0, stream>>>(bbox, W2d);
  convw_t<<<1024, 256, 0, stream>>>(conv_w, Wfb);
  cvt3_bf16<<<512, 256, 0, stream>>>(w1, w2, w3, w1b, w2b, w3b);
  cvt_feat<<<2048, 256, 0, stream>>>(feat, featB);

  // pooling GEMM: per-b, M=144, N=1024 (8 tiles of 128), K=512
  pool_gemm<<<dim3(8, 32), 384, 0, stream>>>(W2d, featB, Xb);

  // conv GEMM: [512,9216] x [1024,9216]^T, 128^2 tiles, SK=8 -> 256 blocks
  gemm128<<<dim3(8, 4, 8), 256, 0, stream>>>(Xb, Wfb, part, 512, 1024, 9216, 1152);
  epi<0><<<(131072 + 255) / 256, 256, 0, stream>>>(part, 8, 131072, 1024,
      conv_b, gamma, beta, mean, var, H0, nullptr);

  // MLP1: [512,1024] x [512,1024]^T, SK=4
  gemm_nt<<<dim3(8, 8, 4), 256, 0, stream>>>(H0, w1b, part, 512, 512, 1024, 256);
  epi<1><<<(65536 + 255) / 256, 256, 0, stream>>>(part, 4, 65536, 512,
      b1, nullptr, nullptr, nullptr, nullptr, H1, nullptr);

  // MLP2: [512,512] x [512,512]^T, SK=4
  gemm_nt<<<dim3(8, 8, 4), 256, 0, stream>>>(H1, w2b, part, 512, 512, 512, 128);
  epi<1><<<(65536 + 255) / 256, 256, 0, stream>>>(part, 4, 65536, 512,
      b2, nullptr, nullptr, nullptr, nullptr, H2, nullptr);

  // MLP3: [512,512] x [512,512]^T, SK=4, fp32 out
  gemm_nt<<<dim3(8, 8, 4), 256, 0, stream>>>(H2, w3b, part, 512, 512, 512, 128);
  epi<2><<<(65536 + 255) / 256, 256, 0, stream>>>(part, 4, 65536, 512,
      b3, nullptr, nullptr, nullptr, nullptr, nullptr, (float*)d_out);
}